// Round 1
// baseline (247.711 us; speedup 1.0000x reference)
//
#include <hip/hip_runtime.h>

#define OUT_DIM 300

__global__ __launch_bounds__(256) void spmm_row_kernel(
    const int* __restrict__ rows,
    const int* __restrict__ cols,
    const float* __restrict__ vals,
    const float* __restrict__ weights,
    const float* __restrict__ bias,
    float* __restrict__ out,
    int nnz)
{
    const int row = blockIdx.x;

    // Binary search segment [lo, hi) for this row in the sorted rows array.
    // Uniform across the block -> scalarizes on the SALU.
    int lo;
    {
        int l = 0, r = nnz;
        while (l < r) {
            int m = (l + r) >> 1;
            if (rows[m] < row) l = m + 1; else r = m;
        }
        lo = l;
    }
    int hi;
    {
        int l = lo, r = nnz;
        while (l < r) {
            int m = (l + r) >> 1;
            if (rows[m] < row + 1) l = m + 1; else r = m;
        }
        hi = l;
    }

    const int t = threadIdx.x;
    const int c0 = t;            // always < 300 (256 threads)
    const int c1 = t + 256;      // valid for t < 44
    const bool has_c1 = (c1 < OUT_DIM);

    float acc0 = 0.0f;
    float acc1 = 0.0f;

    for (int i = lo; i < hi; ++i) {
        const int   c = cols[i];     // uniform load (loop var uniform)
        const float v = vals[i];     // uniform load
        const float* wrow = weights + (long)c * OUT_DIM;
        acc0 += v * wrow[c0];
        if (has_c1) acc1 += v * wrow[c1];
    }

    float* orow = out + (long)row * OUT_DIM;
    orow[c0] = fmaxf(acc0 + bias[c0], 0.0f);
    if (has_c1) orow[c1] = fmaxf(acc1 + bias[c1], 0.0f);
}

extern "C" void kernel_launch(void* const* d_in, const int* in_sizes, int n_in,
                              void* d_out, int out_size, void* d_ws, size_t ws_size,
                              hipStream_t stream) {
    const int*   sp_rows = (const int*)d_in[0];
    const int*   sp_cols = (const int*)d_in[1];
    const float* sp_vals = (const float*)d_in[2];
    const float* weights = (const float*)d_in[3];
    const float* bias    = (const float*)d_in[4];
    float* out = (float*)d_out;

    const int nnz   = in_sizes[0];
    const int batch = out_size / OUT_DIM;

    spmm_row_kernel<<<batch, 256, 0, stream>>>(sp_rows, sp_cols, sp_vals,
                                               weights, bias, out, nnz);
}

// Round 2
// 181.046 us; speedup vs baseline: 1.3682x; 1.3682x over previous
//
#include <hip/hip_runtime.h>

#define OUT_DIM 300
#define OUT_VEC4 75   // 300 floats = 75 float4 (weight rows are 1200B, 16B-aligned)

// Pass 1: CSR row pointers via parallel binary search (rows is sorted).
__global__ __launch_bounds__(256) void row_ptr_kernel(
    const int* __restrict__ rows, int* __restrict__ row_ptr, int nnz, int batch)
{
    int r = blockIdx.x * blockDim.x + threadIdx.x;
    if (r > batch) return;
    int l = 0, h = nnz;
    while (l < h) {
        int m = (l + h) >> 1;
        if (rows[m] < r) l = m + 1; else h = m;
    }
    row_ptr[r] = l;   // lower_bound: row_ptr[batch] == nnz
}

// Pass 2: one 64-lane wave per output row.
// Lane i accumulates float4 output chunk i (cols 4i..4i+3) and, for i<11,
// chunk 64+i. Per nnz: two 16B loads/lane, unrolled x4 for MLP.
__global__ __launch_bounds__(256) void spmm_wave_kernel(
    const int* __restrict__ row_ptr,
    const int* __restrict__ cols,
    const float* __restrict__ vals,
    const float* __restrict__ weights,
    const float* __restrict__ bias,
    float* __restrict__ out,
    int batch)
{
    const int wave = threadIdx.x >> 6;
    const int lane = threadIdx.x & 63;
    const int row  = blockIdx.x * 4 + wave;
    if (row >= batch) return;

    const int lo = row_ptr[row];
    const int hi = row_ptr[row + 1];

    float4 acc0 = make_float4(0.f, 0.f, 0.f, 0.f);
    float4 acc1 = make_float4(0.f, 0.f, 0.f, 0.f);
    const bool tail = (lane < OUT_VEC4 - 64);   // lane < 11

    for (int base = lo; base < hi; base += 64) {
        const int rem = hi - base;
        const int cnt = rem < 64 ? rem : 64;

        // Stage this chunk's (col, val) in registers, coalesced.
        int   c = 0;
        float v = 0.0f;
        if (lane < cnt) {
            c = cols[base + lane];
            v = vals[base + lane];
        }
        // Pad to multiple of 4: dead lanes carry v=0 -> FMA adds 0 (weights finite).
        const int rounds = (cnt + 3) & ~3;
        for (int k = 0; k < rounds; k += 4) {
#pragma unroll
            for (int u = 0; u < 4; ++u) {
                const int   cc = __shfl(c, k + u);
                const float vv = __shfl(v, k + u);
                const float4* wrow = (const float4*)(weights + (size_t)cc * OUT_DIM);
                float4 w0 = wrow[lane];
                float4 w1 = make_float4(0.f, 0.f, 0.f, 0.f);
                if (tail) w1 = wrow[64 + lane];
                acc0.x += vv * w0.x; acc0.y += vv * w0.y;
                acc0.z += vv * w0.z; acc0.w += vv * w0.w;
                acc1.x += vv * w1.x; acc1.y += vv * w1.y;
                acc1.z += vv * w1.z; acc1.w += vv * w1.w;
            }
        }
    }

    const float4* b4 = (const float4*)bias;
    float4* orow = (float4*)(out + (size_t)row * OUT_DIM);

    float4 b0 = b4[lane];
    float4 r0;
    r0.x = fmaxf(acc0.x + b0.x, 0.f);
    r0.y = fmaxf(acc0.y + b0.y, 0.f);
    r0.z = fmaxf(acc0.z + b0.z, 0.f);
    r0.w = fmaxf(acc0.w + b0.w, 0.f);
    orow[lane] = r0;

    if (tail) {
        float4 b1 = b4[64 + lane];
        float4 r1;
        r1.x = fmaxf(acc1.x + b1.x, 0.f);
        r1.y = fmaxf(acc1.y + b1.y, 0.f);
        r1.z = fmaxf(acc1.z + b1.z, 0.f);
        r1.w = fmaxf(acc1.w + b1.w, 0.f);
        orow[64 + lane] = r1;
    }
}

extern "C" void kernel_launch(void* const* d_in, const int* in_sizes, int n_in,
                              void* d_out, int out_size, void* d_ws, size_t ws_size,
                              hipStream_t stream) {
    const int*   sp_rows = (const int*)d_in[0];
    const int*   sp_cols = (const int*)d_in[1];
    const float* sp_vals = (const float*)d_in[2];
    const float* weights = (const float*)d_in[3];
    const float* bias    = (const float*)d_in[4];
    float* out = (float*)d_out;

    const int nnz   = in_sizes[0];
    const int batch = out_size / OUT_DIM;

    int* row_ptr = (int*)d_ws;   // (batch+1) ints

    const int rp_threads = batch + 1;
    row_ptr_kernel<<<(rp_threads + 255) / 256, 256, 0, stream>>>(
        sp_rows, row_ptr, nnz, batch);

    spmm_wave_kernel<<<(batch + 3) / 4, 256, 0, stream>>>(
        row_ptr, sp_cols, sp_vals, weights, bias, out, batch);
}

// Round 3
// 177.900 us; speedup vs baseline: 1.3924x; 1.0177x over previous
//
#include <hip/hip_runtime.h>

#define OUT_DIM 300
#define OUT_VEC4 75   // 300 floats = 75 float4 (weight rows are 1200B, 16B-aligned)

// Pass 1: CSR row pointers via parallel binary search (rows is sorted).
__global__ __launch_bounds__(256) void row_ptr_kernel(
    const int* __restrict__ rows, int* __restrict__ row_ptr, int nnz, int batch)
{
    int r = blockIdx.x * blockDim.x + threadIdx.x;
    if (r > batch) return;
    int l = 0, h = nnz;
    while (l < h) {
        int m = (l + h) >> 1;
        if (rows[m] < r) l = m + 1; else h = m;
    }
    row_ptr[r] = l;   // lower_bound: row_ptr[batch] == nnz
}

// Pass 2: one 64-lane wave per output row. Lane i owns float4 output chunk i
// (cols 4i..4i+3) and, for i<11, chunk 64+i. nnz loop unrolled x8 so each
// wave keeps 16 independent 16B gathers in flight (latency hiding via MLP).
__global__ __launch_bounds__(256) void spmm_wave_kernel(
    const int* __restrict__ row_ptr,
    const int* __restrict__ cols,
    const float* __restrict__ vals,
    const float* __restrict__ weights,
    const float* __restrict__ bias,
    float* __restrict__ out,
    int batch)
{
    const int wave = threadIdx.x >> 6;
    const int lane = threadIdx.x & 63;
    const int row  = blockIdx.x * 4 + wave;
    if (row >= batch) return;

    const int lo = row_ptr[row];
    const int hi = row_ptr[row + 1];

    float4 acc0 = make_float4(0.f, 0.f, 0.f, 0.f);
    float4 acc1 = make_float4(0.f, 0.f, 0.f, 0.f);
    const bool tail = (lane < OUT_VEC4 - 64);   // lane < 11

    for (int base = lo; base < hi; base += 64) {
        const int rem = hi - base;
        const int cnt = rem < 64 ? rem : 64;

        // Stage this chunk's (col, val) in registers, coalesced.
        int   c = 0;
        float v = 0.0f;
        if (lane < cnt) {
            c = cols[base + lane];
            v = vals[base + lane];
        }

        // Pad to multiple of 8: dead slots broadcast v=0 -> FMA adds 0
        // (weights are finite, so 0*w == 0). Extra loads hit L1 (col of lane's
        // stale c, usually c=0 -> hot line).
        const int rounds = (cnt + 7) & ~7;
        for (int k = 0; k < rounds; k += 8) {
            const float4* wr[8];
            float vv[8];
#pragma unroll
            for (int u = 0; u < 8; ++u) {
                const int cc = __shfl(c, k + u);
                vv[u] = __shfl(v, k + u);
                wr[u] = (const float4*)(weights + (size_t)cc * OUT_DIM);
            }
            float4 w0[8];
#pragma unroll
            for (int u = 0; u < 8; ++u) w0[u] = wr[u][lane];
            float4 w1[8];
#pragma unroll
            for (int u = 0; u < 8; ++u) {
                w1[u] = make_float4(0.f, 0.f, 0.f, 0.f);
                if (tail) w1[u] = wr[u][64 + lane];
            }
#pragma unroll
            for (int u = 0; u < 8; ++u) {
                acc0.x += vv[u] * w0[u].x; acc0.y += vv[u] * w0[u].y;
                acc0.z += vv[u] * w0[u].z; acc0.w += vv[u] * w0[u].w;
                acc1.x += vv[u] * w1[u].x; acc1.y += vv[u] * w1[u].y;
                acc1.z += vv[u] * w1[u].z; acc1.w += vv[u] * w1[u].w;
            }
        }
    }

    const float4* b4 = (const float4*)bias;
    float4* orow = (float4*)(out + (size_t)row * OUT_DIM);

    float4 b0 = b4[lane];
    float4 r0;
    r0.x = fmaxf(acc0.x + b0.x, 0.f);
    r0.y = fmaxf(acc0.y + b0.y, 0.f);
    r0.z = fmaxf(acc0.z + b0.z, 0.f);
    r0.w = fmaxf(acc0.w + b0.w, 0.f);
    orow[lane] = r0;

    if (tail) {
        float4 b1 = b4[64 + lane];
        float4 r1;
        r1.x = fmaxf(acc1.x + b1.x, 0.f);
        r1.y = fmaxf(acc1.y + b1.y, 0.f);
        r1.z = fmaxf(acc1.z + b1.z, 0.f);
        r1.w = fmaxf(acc1.w + b1.w, 0.f);
        orow[64 + lane] = r1;
    }
}

extern "C" void kernel_launch(void* const* d_in, const int* in_sizes, int n_in,
                              void* d_out, int out_size, void* d_ws, size_t ws_size,
                              hipStream_t stream) {
    const int*   sp_rows = (const int*)d_in[0];
    const int*   sp_cols = (const int*)d_in[1];
    const float* sp_vals = (const float*)d_in[2];
    const float* weights = (const float*)d_in[3];
    const float* bias    = (const float*)d_in[4];
    float* out = (float*)d_out;

    const int nnz   = in_sizes[0];
    const int batch = out_size / OUT_DIM;

    int* row_ptr = (int*)d_ws;   // (batch+1) ints

    const int rp_threads = batch + 1;
    row_ptr_kernel<<<(rp_threads + 255) / 256, 256, 0, stream>>>(
        sp_rows, row_ptr, nnz, batch);

    spmm_wave_kernel<<<(batch + 3) / 4, 256, 0, stream>>>(
        row_ptr, sp_cols, sp_vals, weights, bias, out, batch);
}

// Round 4
// 148.421 us; speedup vs baseline: 1.6690x; 1.1986x over previous
//
#include <hip/hip_runtime.h>

#define OUT_DIM 300
#define OUT_VEC4 75    // 300 floats  = 75 float4  (fp32 path)
#define OUT_VECB 75    // 300 bf16    = 75 ushort4 (bf16 path, 8B chunks)
#define IN_DIM_GUESS 0 // input dim derived from in_sizes

__device__ __forceinline__ unsigned short f2bf_rne(float f) {
    unsigned int u = __float_as_uint(f);
    u += 0x7FFFu + ((u >> 16) & 1u);   // round-to-nearest-even
    return (unsigned short)(u >> 16);
}
__device__ __forceinline__ float bf2f(unsigned short s) {
    return __uint_as_float(((unsigned int)s) << 16);
}

// Pass 0: CSR row pointers via parallel binary search (rows is sorted).
__global__ __launch_bounds__(256) void row_ptr_kernel(
    const int* __restrict__ rows, int* __restrict__ row_ptr, int nnz, int batch)
{
    int r = blockIdx.x * blockDim.x + threadIdx.x;
    if (r > batch) return;
    int l = 0, h = nnz;
    while (l < h) {
        int m = (l + h) >> 1;
        if (rows[m] < r) l = m + 1; else h = m;
    }
    row_ptr[r] = l;
}

// Pass 0b: repack fp32 weights -> bf16 (RNE). Streaming, ~54MB traffic.
__global__ __launch_bounds__(256) void repack_kernel(
    const float4* __restrict__ w, ushort4* __restrict__ wbf, int n4)
{
    int i = blockIdx.x * blockDim.x + threadIdx.x;
    int stride = gridDim.x * blockDim.x;
    for (; i < n4; i += stride) {
        float4 f = w[i];
        ushort4 o;
        o.x = f2bf_rne(f.x); o.y = f2bf_rne(f.y);
        o.z = f2bf_rne(f.z); o.w = f2bf_rne(f.w);
        wbf[i] = o;
    }
}

// Pass 1 (bf16): one wave per row; lane i owns bf16x4 chunk i (cols 4i..4i+3)
// and for i<11 chunk 64+i. nnz loop unrolled x8 for MLP; gathered bytes
// halved vs fp32 (600B/row).
__global__ __launch_bounds__(256) void spmm_wave_bf16_kernel(
    const int* __restrict__ row_ptr,
    const int* __restrict__ cols,
    const float* __restrict__ vals,
    const unsigned short* __restrict__ wbf,
    const float* __restrict__ bias,
    float* __restrict__ out,
    int batch)
{
    const int wave = threadIdx.x >> 6;
    const int lane = threadIdx.x & 63;
    const int row  = blockIdx.x * 4 + wave;
    if (row >= batch) return;

    const int lo = row_ptr[row];
    const int hi = row_ptr[row + 1];

    float4 acc0 = make_float4(0.f, 0.f, 0.f, 0.f);
    float4 acc1 = make_float4(0.f, 0.f, 0.f, 0.f);
    const bool tail = (lane < OUT_VECB - 64);   // lane < 11

    for (int base = lo; base < hi; base += 64) {
        const int rem = hi - base;
        const int cnt = rem < 64 ? rem : 64;

        int   c = 0;
        float v = 0.0f;
        if (lane < cnt) {
            c = cols[base + lane];
            v = vals[base + lane];
        }

        const int rounds = (cnt + 7) & ~7;
        for (int k = 0; k < rounds; k += 8) {
            const ushort4* wr[8];
            float vv[8];
#pragma unroll
            for (int u = 0; u < 8; ++u) {
                const int cc = __shfl(c, k + u);
                vv[u] = __shfl(v, k + u);
                wr[u] = (const ushort4*)(wbf + (size_t)cc * OUT_DIM);
            }
            ushort4 w0[8];
#pragma unroll
            for (int u = 0; u < 8; ++u) w0[u] = wr[u][lane];
            ushort4 w1[8];
#pragma unroll
            for (int u = 0; u < 8; ++u) {
                w1[u] = make_ushort4(0, 0, 0, 0);
                if (tail) w1[u] = wr[u][64 + lane];
            }
#pragma unroll
            for (int u = 0; u < 8; ++u) {
                acc0.x += vv[u] * bf2f(w0[u].x);
                acc0.y += vv[u] * bf2f(w0[u].y);
                acc0.z += vv[u] * bf2f(w0[u].z);
                acc0.w += vv[u] * bf2f(w0[u].w);
                acc1.x += vv[u] * bf2f(w1[u].x);
                acc1.y += vv[u] * bf2f(w1[u].y);
                acc1.z += vv[u] * bf2f(w1[u].z);
                acc1.w += vv[u] * bf2f(w1[u].w);
            }
        }
    }

    const float4* b4 = (const float4*)bias;
    float4* orow = (float4*)(out + (size_t)row * OUT_DIM);

    float4 b0 = b4[lane];
    float4 r0;
    r0.x = fmaxf(acc0.x + b0.x, 0.f);
    r0.y = fmaxf(acc0.y + b0.y, 0.f);
    r0.z = fmaxf(acc0.z + b0.z, 0.f);
    r0.w = fmaxf(acc0.w + b0.w, 0.f);
    orow[lane] = r0;

    if (tail) {
        float4 b1 = b4[64 + lane];
        float4 r1;
        r1.x = fmaxf(acc1.x + b1.x, 0.f);
        r1.y = fmaxf(acc1.y + b1.y, 0.f);
        r1.z = fmaxf(acc1.z + b1.z, 0.f);
        r1.w = fmaxf(acc1.w + b1.w, 0.f);
        orow[64 + lane] = r1;
    }
}

// Fallback fp32 path (used only if d_ws is too small for the bf16 copy).
__global__ __launch_bounds__(256) void spmm_wave_f32_kernel(
    const int* __restrict__ row_ptr,
    const int* __restrict__ cols,
    const float* __restrict__ vals,
    const float* __restrict__ weights,
    const float* __restrict__ bias,
    float* __restrict__ out,
    int batch)
{
    const int wave = threadIdx.x >> 6;
    const int lane = threadIdx.x & 63;
    const int row  = blockIdx.x * 4 + wave;
    if (row >= batch) return;

    const int lo = row_ptr[row];
    const int hi = row_ptr[row + 1];

    float4 acc0 = make_float4(0.f, 0.f, 0.f, 0.f);
    float4 acc1 = make_float4(0.f, 0.f, 0.f, 0.f);
    const bool tail = (lane < OUT_VEC4 - 64);

    for (int base = lo; base < hi; base += 64) {
        const int rem = hi - base;
        const int cnt = rem < 64 ? rem : 64;
        int   c = 0;
        float v = 0.0f;
        if (lane < cnt) { c = cols[base + lane]; v = vals[base + lane]; }
        const int rounds = (cnt + 7) & ~7;
        for (int k = 0; k < rounds; k += 8) {
#pragma unroll
            for (int u = 0; u < 8; ++u) {
                const int   cc = __shfl(c, k + u);
                const float vv = __shfl(v, k + u);
                const float4* wrow = (const float4*)(weights + (size_t)cc * OUT_DIM);
                float4 w0 = wrow[lane];
                acc0.x += vv * w0.x; acc0.y += vv * w0.y;
                acc0.z += vv * w0.z; acc0.w += vv * w0.w;
                if (tail) {
                    float4 w1 = wrow[64 + lane];
                    acc1.x += vv * w1.x; acc1.y += vv * w1.y;
                    acc1.z += vv * w1.z; acc1.w += vv * w1.w;
                }
            }
        }
    }

    const float4* b4 = (const float4*)bias;
    float4* orow = (float4*)(out + (size_t)row * OUT_DIM);
    float4 b0 = b4[lane];
    float4 r0;
    r0.x = fmaxf(acc0.x + b0.x, 0.f);
    r0.y = fmaxf(acc0.y + b0.y, 0.f);
    r0.z = fmaxf(acc0.z + b0.z, 0.f);
    r0.w = fmaxf(acc0.w + b0.w, 0.f);
    orow[lane] = r0;
    if (tail) {
        float4 b1 = b4[64 + lane];
        float4 r1;
        r1.x = fmaxf(acc1.x + b1.x, 0.f);
        r1.y = fmaxf(acc1.y + b1.y, 0.f);
        r1.z = fmaxf(acc1.z + b1.z, 0.f);
        r1.w = fmaxf(acc1.w + b1.w, 0.f);
        orow[64 + lane] = r1;
    }
}

extern "C" void kernel_launch(void* const* d_in, const int* in_sizes, int n_in,
                              void* d_out, int out_size, void* d_ws, size_t ws_size,
                              hipStream_t stream) {
    const int*   sp_rows = (const int*)d_in[0];
    const int*   sp_cols = (const int*)d_in[1];
    const float* sp_vals = (const float*)d_in[2];
    const float* weights = (const float*)d_in[3];
    const float* bias    = (const float*)d_in[4];
    float* out = (float*)d_out;

    const int nnz    = in_sizes[0];
    const int w_elts = in_sizes[3];           // INPUT_DIM * OUT_DIM
    const int batch  = out_size / OUT_DIM;

    // ws layout: [row_ptr: (batch+1) ints][pad to 256][wbf: w_elts bf16]
    size_t rp_bytes  = (size_t)(batch + 1) * sizeof(int);
    size_t wbf_off   = (rp_bytes + 255) & ~(size_t)255;
    size_t need      = wbf_off + (size_t)w_elts * sizeof(unsigned short);

    int* row_ptr = (int*)d_ws;

    row_ptr_kernel<<<(batch + 1 + 255) / 256, 256, 0, stream>>>(
        sp_rows, row_ptr, nnz, batch);

    if (ws_size >= need) {
        unsigned short* wbf = (unsigned short*)((char*)d_ws + wbf_off);
        const int n4 = w_elts / 4;   // 9,000,000 / 4 — divisible
        repack_kernel<<<1024, 256, 0, stream>>>(
            (const float4*)weights, (ushort4*)wbf, n4);
        spmm_wave_bf16_kernel<<<(batch + 3) / 4, 256, 0, stream>>>(
            row_ptr, sp_cols, sp_vals, wbf, bias, out, batch);
    } else {
        spmm_wave_f32_kernel<<<(batch + 3) / 4, 256, 0, stream>>>(
            row_ptr, sp_cols, sp_vals, weights, bias, out, batch);
    }
}

// Round 5
// 146.070 us; speedup vs baseline: 1.6958x; 1.0161x over previous
//
#include <hip/hip_runtime.h>

#define OUT_DIM 300

typedef _Float16 half4_t __attribute__((ext_vector_type(4)));
typedef _Float16 half2_t __attribute__((ext_vector_type(2)));

// ---------------------------------------------------------------------------
// Pass 0: row_ptr via boundary scatter over the sorted rows array. O(nnz),
// coalesced; replaces 20-dependent-load binary search (~15us -> ~2us).
__global__ __launch_bounds__(256) void row_ptr_scatter(
    const int* __restrict__ rows, int* __restrict__ row_ptr, int nnz, int batch)
{
    int i = blockIdx.x * 256 + threadIdx.x;
    if (i >= nnz) return;
    int r = rows[i];
    int prev = (i == 0) ? -1 : rows[i - 1];
    for (int q = prev + 1; q <= r; ++q) row_ptr[q] = i;     // lower_bound fill
    if (i == nnz - 1)
        for (int q = r + 1; q <= batch; ++q) row_ptr[q] = nnz;
}

// ---------------------------------------------------------------------------
// Pass 0b: repack fp32 weights -> f16, slice-major. 4 column slices:
// s=0..2 cover 76 cols (152 B rows), s=3 covers 72 cols (144 B rows).
// Slice s base = s * in_dim * 152 (total exactly in_dim*600 bytes = 18.0 MB).
__global__ __launch_bounds__(256) void repack_f16_sliced(
    const float* __restrict__ w, unsigned char* __restrict__ wf, int in_dim)
{
    const int PPR = OUT_DIM / 2;          // 150 float-pairs per row
    int i = blockIdx.x * 256 + threadIdx.x;
    if (i >= in_dim * PPR) return;
    int row = i / PPR;
    int p   = i - row * PPR;              // pair index, col = 2p
    int s   = p / 38;                     // 38 pairs per 76-col slice (s==3: 36)
    int pc  = p - s * 38;
    int stride = (s == 3) ? 144 : 152;
    size_t dst = (size_t)s * in_dim * 152 + (size_t)row * stride + (size_t)pc * 4;
    float2 f = *(const float2*)(w + (size_t)row * OUT_DIM + 2 * p);
    half2_t h;
    h.x = (_Float16)f.x;
    h.y = (_Float16)f.y;
    *(half2_t*)(wf + dst) = h;
}

// ---------------------------------------------------------------------------
// Pass 1: XCD-sliced gather SpMM. Block b: rowgroup b>>2 (4 rows, one per
// wave), slice b&3. With round-robin block->XCD dispatch, XCD x sees only
// slice x%4 -> per-XCD gather working set 4.56 MB ~= one L2.
// Wave: 2 half-wave groups (grp=lane>>5), each handles one nnz per round;
// idx=lane&31 owns half4 chunk idx (cols 76*s + 4*idx ..+3), active idx<nch.
__global__ __launch_bounds__(256) void spmm_sliced_f16(
    const int* __restrict__ row_ptr,
    const int* __restrict__ cols,
    const float* __restrict__ vals,
    const unsigned char* __restrict__ wf,
    const float* __restrict__ bias,
    float* __restrict__ out,
    int batch, int in_dim)
{
    const int slice = blockIdx.x & 3;
    const int wave  = threadIdx.x >> 6;
    const int lane  = threadIdx.x & 63;
    const int row   = (blockIdx.x >> 2) * 4 + wave;
    if (row >= batch) return;

    const int grp = lane >> 5;
    const int idx = lane & 31;

    const int nch    = (slice == 3) ? 18 : 19;   // half4 chunks in this slice
    const int stride = (slice == 3) ? 144 : 152; // bytes per weight row
    const size_t sbase = (size_t)slice * in_dim * 152;

    // Per-lane base into the slice (idx>=nch lanes read junk pad; their acc
    // is never reduced or stored).
    const unsigned char* wlane = wf + sbase + (size_t)idx * 8;

    const int lo = row_ptr[row];
    const int hi = row_ptr[row + 1];

    float4 acc = make_float4(0.f, 0.f, 0.f, 0.f);

    for (int base = lo; base < hi; base += 64) {
        const int rem = hi - base;
        const int cnt = rem < 64 ? rem : 64;

        int   off = 0;
        float v   = 0.0f;
        if (lane < cnt) {
            int c = cols[base + lane];
            v   = vals[base + lane];
            off = c * stride;
        }

        // 2 nnz per round (one per half-wave group); unroll x4 for MLP.
        const int rounds = (cnt + 1) >> 1;
        const int rr = (rounds + 3) & ~3;
        for (int r = 0; r < rr; r += 4) {
#pragma unroll
            for (int u = 0; u < 4; ++u) {
                const int src = 2 * (r + u) + grp;       // < 64 always
                const int   ob = __shfl(off, src);       // dead rounds: 0
                const float vb = __shfl(v,   src);       // dead rounds: 0
                half4_t wv = *(const half4_t*)(wlane + ob);
                acc.x = fmaf(vb, (float)wv.x, acc.x);
                acc.y = fmaf(vb, (float)wv.y, acc.y);
                acc.z = fmaf(vb, (float)wv.z, acc.z);
                acc.w = fmaf(vb, (float)wv.w, acc.w);
            }
        }
    }

    // Fold group 1 into group 0 (same chunk, disjoint nnz subsets).
    acc.x += __shfl_down(acc.x, 32);
    acc.y += __shfl_down(acc.y, 32);
    acc.z += __shfl_down(acc.z, 32);
    acc.w += __shfl_down(acc.w, 32);

    if (grp == 0 && idx < nch) {
        const int colb = 76 * slice + 4 * idx;           // <= 296, float4-aligned
        const float4 b = *(const float4*)(bias + colb);
        float4 rv;
        rv.x = fmaxf(acc.x + b.x, 0.f);
        rv.y = fmaxf(acc.y + b.y, 0.f);
        rv.z = fmaxf(acc.z + b.z, 0.f);
        rv.w = fmaxf(acc.w + b.w, 0.f);
        *(float4*)(out + (size_t)row * OUT_DIM + colb) = rv;
    }
}

// ---------------------------------------------------------------------------
// Fallback fp32 path (only if d_ws can't hold the f16 copy).
__global__ __launch_bounds__(256) void spmm_wave_f32_kernel(
    const int* __restrict__ row_ptr,
    const int* __restrict__ cols,
    const float* __restrict__ vals,
    const float* __restrict__ weights,
    const float* __restrict__ bias,
    float* __restrict__ out,
    int batch)
{
    const int wave = threadIdx.x >> 6;
    const int lane = threadIdx.x & 63;
    const int row  = blockIdx.x * 4 + wave;
    if (row >= batch) return;

    const int lo = row_ptr[row];
    const int hi = row_ptr[row + 1];

    float4 acc0 = make_float4(0.f, 0.f, 0.f, 0.f);
    float4 acc1 = make_float4(0.f, 0.f, 0.f, 0.f);
    const bool tail = (lane < 75 - 64);

    for (int base = lo; base < hi; base += 64) {
        const int rem = hi - base;
        const int cnt = rem < 64 ? rem : 64;
        int   c = 0;
        float v = 0.0f;
        if (lane < cnt) { c = cols[base + lane]; v = vals[base + lane]; }
        const int rounds = (cnt + 7) & ~7;
        for (int k = 0; k < rounds; k += 8) {
#pragma unroll
            for (int u = 0; u < 8; ++u) {
                const int   cc = __shfl(c, k + u);
                const float vv = __shfl(v, k + u);
                const float4* wrow = (const float4*)(weights + (size_t)cc * OUT_DIM);
                float4 w0 = wrow[lane];
                acc0.x += vv * w0.x; acc0.y += vv * w0.y;
                acc0.z += vv * w0.z; acc0.w += vv * w0.w;
                if (tail) {
                    float4 w1 = wrow[64 + lane];
                    acc1.x += vv * w1.x; acc1.y += vv * w1.y;
                    acc1.z += vv * w1.z; acc1.w += vv * w1.w;
                }
            }
        }
    }

    const float4* b4 = (const float4*)bias;
    float4* orow = (float4*)(out + (size_t)row * OUT_DIM);
    float4 b0 = b4[lane];
    float4 r0;
    r0.x = fmaxf(acc0.x + b0.x, 0.f);
    r0.y = fmaxf(acc0.y + b0.y, 0.f);
    r0.z = fmaxf(acc0.z + b0.z, 0.f);
    r0.w = fmaxf(acc0.w + b0.w, 0.f);
    orow[lane] = r0;
    if (tail) {
        float4 b1 = b4[64 + lane];
        float4 r1;
        r1.x = fmaxf(acc1.x + b1.x, 0.f);
        r1.y = fmaxf(acc1.y + b1.y, 0.f);
        r1.z = fmaxf(acc1.z + b1.z, 0.f);
        r1.w = fmaxf(acc1.w + b1.w, 0.f);
        orow[64 + lane] = r1;
    }
}

// ---------------------------------------------------------------------------
extern "C" void kernel_launch(void* const* d_in, const int* in_sizes, int n_in,
                              void* d_out, int out_size, void* d_ws, size_t ws_size,
                              hipStream_t stream) {
    const int*   sp_rows = (const int*)d_in[0];
    const int*   sp_cols = (const int*)d_in[1];
    const float* sp_vals = (const float*)d_in[2];
    const float* weights = (const float*)d_in[3];
    const float* bias    = (const float*)d_in[4];
    float* out = (float*)d_out;

    const int nnz    = in_sizes[0];
    const int w_elts = in_sizes[3];
    const int in_dim = w_elts / OUT_DIM;           // 30000
    const int batch  = out_size / OUT_DIM;         // 16384

    // ws layout: [row_ptr: (batch+1) ints][pad->256][wf16: in_dim*600 B][pad 256]
    size_t rp_bytes = (size_t)(batch + 1) * sizeof(int);
    size_t wf_off   = (rp_bytes + 255) & ~(size_t)255;
    size_t need     = wf_off + (size_t)in_dim * 600 + 256;  // +256: OOB-read pad

    int* row_ptr = (int*)d_ws;

    row_ptr_scatter<<<(nnz + 255) / 256, 256, 0, stream>>>(
        sp_rows, row_ptr, nnz, batch);

    if (ws_size >= need) {
        unsigned char* wf = (unsigned char*)d_ws + wf_off;
        const int pairs = in_dim * (OUT_DIM / 2);
        repack_f16_sliced<<<(pairs + 255) / 256, 256, 0, stream>>>(
            weights, wf, in_dim);
        const int rowgroups = (batch + 3) / 4;
        spmm_sliced_f16<<<rowgroups * 4, 256, 0, stream>>>(
            row_ptr, sp_cols, sp_vals, wf, bias, out, batch, in_dim);
    } else {
        spmm_wave_f32_kernel<<<(batch + 3) / 4, 256, 0, stream>>>(
            row_ptr, sp_cols, sp_vals, weights, bias, out, batch);
    }
}

// Round 6
// 139.969 us; speedup vs baseline: 1.7698x; 1.0436x over previous
//
#include <hip/hip_runtime.h>

#define OUT_DIM 300

typedef _Float16 half4_t __attribute__((ext_vector_type(4)));
typedef _Float16 half2_t __attribute__((ext_vector_type(2)));

// ---------------------------------------------------------------------------
// Pass 0: row_ptr via boundary scatter over the sorted rows array. O(nnz).
__global__ __launch_bounds__(256) void row_ptr_scatter(
    const int* __restrict__ rows, int* __restrict__ row_ptr, int nnz, int batch)
{
    int i = blockIdx.x * 256 + threadIdx.x;
    if (i >= nnz) return;
    int r = rows[i];
    int prev = (i == 0) ? -1 : rows[i - 1];
    for (int q = prev + 1; q <= r; ++q) row_ptr[q] = i;
    if (i == nnz - 1)
        for (int q = r + 1; q <= batch; ++q) row_ptr[q] = nnz;
}

// ---------------------------------------------------------------------------
// Pass 0b: repack fp32 -> f16, slice-major, 4 slices {76,76,76,72} cols.
// tierA: all slice rows stride 160 B (rows span exactly 3 cache lines).
// tierB: packed strides 152/152/152/144 (R5 layout, smaller ws).
__global__ __launch_bounds__(256) void repack_f16_sliced(
    const float* __restrict__ w, unsigned char* __restrict__ wf,
    int in_dim, int tierA)
{
    const int PPR = OUT_DIM / 2;          // 150 float-pairs per row
    int i = blockIdx.x * 256 + threadIdx.x;
    if (i >= in_dim * PPR) return;
    int row = i / PPR;
    int p   = i - row * PPR;              // pair index, col = 2p
    int s   = p / 38;                     // 38 pairs/slice (s==3: 36)
    int pc  = p - s * 38;
    int stride = tierA ? 160 : ((s == 3) ? 144 : 152);
    size_t sbase = (size_t)s * in_dim * (tierA ? 160 : 152);
    size_t dst = sbase + (size_t)row * stride + (size_t)pc * 4;
    float2 f = *(const float2*)(w + (size_t)row * OUT_DIM + 2 * p);
    half2_t h;
    h.x = (_Float16)f.x;
    h.y = (_Float16)f.y;
    *(half2_t*)(wf + dst) = h;
}

// ---------------------------------------------------------------------------
// Pass 1: XCD-sliced SpMM, 3 nnz per wave-round.
// Block b: rowgroup b>>2 (4 rows, one per wave), slice b&3 (matches
// round-robin block->XCD so XCD x touches only slice x%4).
// Wave lanes: grp = lane/nch (0..2 real, 3 = prefetch), ch = lane - grp*nch
// fixed per lane -> register float4 accumulator per lane. Per round r, grp g
// processes nnz 3r+g: broadcast (off,val) via wave-private LDS slot (zero-
// padded, so dead rounds contribute 0 with in-bounds base reads).
__global__ __launch_bounds__(256) void spmm_sliced3(
    const int* __restrict__ row_ptr,
    const int* __restrict__ cols,
    const float* __restrict__ vals,
    const unsigned char* __restrict__ wf,
    const float* __restrict__ bias,
    float* __restrict__ out,
    int batch, int in_dim, int tierA)
{
    __shared__ uint2 sh[4][76];

    const int slice = blockIdx.x & 3;
    const int wave  = threadIdx.x >> 6;
    const int lane  = threadIdx.x & 63;
    const int row   = (blockIdx.x >> 2) * 4 + wave;
    if (row >= batch) return;

    const int nch    = (slice == 3) ? 18 : 19;
    const int stride = tierA ? 160 : ((slice == 3) ? 144 : 152);
    const unsigned char* wslice = wf + (size_t)slice * in_dim * (tierA ? 160 : 152);

    int grp = lane / nch;                 // 0..3 (grp 3 = prefetch lanes)
    int ch  = lane - grp * nch;
    const int choff = ch * 8;

    uint2* shw = sh[wave];                // wave-private: no __syncthreads

    const int lo = row_ptr[row];
    const int hi = row_ptr[row + 1];

    float4 acc = make_float4(0.f, 0.f, 0.f, 0.f);

    for (int base = lo; base < hi; base += 64) {
        const int rem = hi - base;
        const int cnt = rem < 64 ? rem : 64;

        uint2 ov = make_uint2(0u, 0u);
        if (lane < cnt) {
            int c = cols[base + lane];
            ov.x = (unsigned)(c * stride);
            ov.y = __float_as_uint(vals[base + lane]);
        }
        shw[lane] = ov;
        if (lane < 12) shw[64 + lane] = make_uint2(0u, 0u);  // pad slots 64..75

        const int rr  = (cnt + 2) / 3;          // rounds (3 nnz each), <= 22
        const int rrp = (rr + 3) & ~3;          // <= 24 -> max slot 3*23+3 = 72
        for (int r0 = 0; r0 < rrp; r0 += 4) {
#pragma unroll
            for (int u = 0; u < 4; ++u) {
                uint2 q = shw[3 * (r0 + u) + grp];   // LDS broadcast per grp
                float v = __uint_as_float(q.y);
                half4_t wv = *(const half4_t*)(wslice + q.x + choff);
                acc.x += v * (float)wv.x;
                acc.y += v * (float)wv.y;
                acc.z += v * (float)wv.z;
                acc.w += v * (float)wv.w;
            }
        }
        // grp 3 lanes accumulate garbage (prefetch only); never folded/stored.
    }

    // Fold the 3 real groups: lane i (<nch) += lanes i+nch, i+2*nch.
    float ax = acc.x + __shfl_down(acc.x, nch) + __shfl_down(acc.x, 2 * nch);
    float ay = acc.y + __shfl_down(acc.y, nch) + __shfl_down(acc.y, 2 * nch);
    float az = acc.z + __shfl_down(acc.z, nch) + __shfl_down(acc.z, 2 * nch);
    float aw = acc.w + __shfl_down(acc.w, nch) + __shfl_down(acc.w, 2 * nch);

    if (lane < nch) {
        const int colb = 76 * slice + 4 * lane;          // <= 296, 16B-aligned
        const float4 b = *(const float4*)(bias + colb);
        float4 rv;
        rv.x = fmaxf(ax + b.x, 0.f);
        rv.y = fmaxf(ay + b.y, 0.f);
        rv.z = fmaxf(az + b.z, 0.f);
        rv.w = fmaxf(aw + b.w, 0.f);
        *(float4*)(out + (size_t)row * OUT_DIM + colb) = rv;
    }
}

// ---------------------------------------------------------------------------
// Fallback fp32 path (only if d_ws can't hold the f16 copy).
__global__ __launch_bounds__(256) void spmm_wave_f32_kernel(
    const int* __restrict__ row_ptr,
    const int* __restrict__ cols,
    const float* __restrict__ vals,
    const float* __restrict__ weights,
    const float* __restrict__ bias,
    float* __restrict__ out,
    int batch)
{
    const int wave = threadIdx.x >> 6;
    const int lane = threadIdx.x & 63;
    const int row  = blockIdx.x * 4 + wave;
    if (row >= batch) return;

    const int lo = row_ptr[row];
    const int hi = row_ptr[row + 1];

    float4 acc0 = make_float4(0.f, 0.f, 0.f, 0.f);
    float4 acc1 = make_float4(0.f, 0.f, 0.f, 0.f);
    const bool tail = (lane < 75 - 64);

    for (int base = lo; base < hi; base += 64) {
        const int rem = hi - base;
        const int cnt = rem < 64 ? rem : 64;
        int   c = 0;
        float v = 0.0f;
        if (lane < cnt) { c = cols[base + lane]; v = vals[base + lane]; }
        const int rounds = (cnt + 7) & ~7;
        for (int k = 0; k < rounds; k += 8) {
#pragma unroll
            for (int u = 0; u < 8; ++u) {
                const int   cc = __shfl(c, k + u);
                const float vv = __shfl(v, k + u);
                const float4* wrow = (const float4*)(weights + (size_t)cc * OUT_DIM);
                float4 w0 = wrow[lane];
                acc0.x += vv * w0.x; acc0.y += vv * w0.y;
                acc0.z += vv * w0.z; acc0.w += vv * w0.w;
                if (tail) {
                    float4 w1 = wrow[64 + lane];
                    acc1.x += vv * w1.x; acc1.y += vv * w1.y;
                    acc1.z += vv * w1.z; acc1.w += vv * w1.w;
                }
            }
        }
    }

    const float4* b4 = (const float4*)bias;
    float4* orow = (float4*)(out + (size_t)row * OUT_DIM);
    float4 b0 = b4[lane];
    float4 r0;
    r0.x = fmaxf(acc0.x + b0.x, 0.f);
    r0.y = fmaxf(acc0.y + b0.y, 0.f);
    r0.z = fmaxf(acc0.z + b0.z, 0.f);
    r0.w = fmaxf(acc0.w + b0.w, 0.f);
    orow[lane] = r0;
    if (tail) {
        float4 b1 = b4[64 + lane];
        float4 r1;
        r1.x = fmaxf(acc1.x + b1.x, 0.f);
        r1.y = fmaxf(acc1.y + b1.y, 0.f);
        r1.z = fmaxf(acc1.z + b1.z, 0.f);
        r1.w = fmaxf(acc1.w + b1.w, 0.f);
        orow[64 + lane] = r1;
    }
}

// ---------------------------------------------------------------------------
extern "C" void kernel_launch(void* const* d_in, const int* in_sizes, int n_in,
                              void* d_out, int out_size, void* d_ws, size_t ws_size,
                              hipStream_t stream) {
    const int*   sp_rows = (const int*)d_in[0];
    const int*   sp_cols = (const int*)d_in[1];
    const float* sp_vals = (const float*)d_in[2];
    const float* weights = (const float*)d_in[3];
    const float* bias    = (const float*)d_in[4];
    float* out = (float*)d_out;

    const int nnz    = in_sizes[0];
    const int w_elts = in_sizes[3];
    const int in_dim = w_elts / OUT_DIM;           // 30000
    const int batch  = out_size / OUT_DIM;         // 16384

    // ws layout: [row_ptr: (batch+1) ints][pad->256][wf16][pad 256]
    size_t rp_bytes = (size_t)(batch + 1) * sizeof(int);
    size_t wf_off   = (rp_bytes + 255) & ~(size_t)255;
    size_t needA    = wf_off + (size_t)in_dim * 640 + 256;  // stride-160 layout
    size_t needB    = wf_off + (size_t)in_dim * 600 + 256;  // packed layout

    int* row_ptr = (int*)d_ws;

    row_ptr_scatter<<<(nnz + 255) / 256, 256, 0, stream>>>(
        sp_rows, row_ptr, nnz, batch);

    if (ws_size >= needB) {
        const int tierA = (ws_size >= needA) ? 1 : 0;
        unsigned char* wf = (unsigned char*)d_ws + wf_off;
        const int pairs = in_dim * (OUT_DIM / 2);
        repack_f16_sliced<<<(pairs + 255) / 256, 256, 0, stream>>>(
            weights, wf, in_dim, tierA);
        const int rowgroups = (batch + 3) / 4;
        spmm_sliced3<<<rowgroups * 4, 256, 0, stream>>>(
            row_ptr, sp_cols, sp_vals, wf, bias, out, batch, in_dim, tierA);
    } else {
        spmm_wave_f32_kernel<<<(batch + 3) / 4, 256, 0, stream>>>(
            row_ptr, sp_cols, sp_vals, weights, bias, out, batch);
    }
}